// Round 2
// baseline (1922.307 us; speedup 1.0000x reference)
//
#include <hip/hip_runtime.h>
#include <math.h>

// Problem constants (match setup_inputs)
#define NPTS 4096
#define NB   16
// L1: K=643 (pad 656), M=256 ; L2: K=256, M=512 ; L3: K=512, M=1024

// ---- workspace layout (float offsets) ----
static const size_t OFF_Y1  = 0;                         // 16*256*4096  = 16,777,216
static const size_t OFF_Y2  = 16777216;                  // 16*512*4096  = 33,554,432
static const size_t OFF_W1P = 50331648;                  // 256*656     =    167,936
static const size_t OFF_A1  = OFF_W1P + 167936;          // 256
static const size_t OFF_SH1 = OFF_A1  + 256;             // 256
static const size_t OFF_A2  = OFF_SH1 + 256;             // 512
static const size_t OFF_SH2 = OFF_A2  + 512;             // 512
static const size_t OFF_A3  = OFF_SH2 + 512;             // 1024
static const size_t OFF_SH3 = OFF_A3  + 1024;            // 1024
static const size_t OFF_P1S = OFF_SH3 + 1024;            // 256 slots * 256  = 65536
static const size_t OFF_P1Q = OFF_P1S + 65536;
static const size_t OFF_P2S = OFF_P1Q + 65536;           // 128 slots * 512  = 65536
static const size_t OFF_P2Q = OFF_P2S + 65536;
static const size_t OFF_P3S = OFF_P2Q + 65536;           // 64 slots * 1024  = 65536
static const size_t OFF_P3Q = OFF_P3S + 65536;
static const size_t OFF_PMX = OFF_P3Q + 65536;           // 16*1024*4 = 65536
static const size_t OFF_PMN = OFF_PMX + 65536;
// total = OFF_PMN + 65536 = 51,027,456 floats = ~195 MiB

#define FLT_BIG 3.402823466e38f

// ---- pad W1 (K=643 -> 656, zeros) ----
__global__ void pad_w1_k(const float* __restrict__ W1, float* __restrict__ Wp) {
    int idx = blockIdx.x * 256 + threadIdx.x;
    if (idx >= 256 * 656) return;
    int m = idx / 656, k = idx - m * 656;
    Wp[idx] = (k < 643) ? W1[m * 643 + k] : 0.f;
}

// ---- fused GEMM:  y[b,m,n] = sum_k W[m,k] * f(X[b,k,n]) + bias[m]
//      f = identity (L1) or relu(a_in[k]*x + sh_in[k]) (L2/L3)
//      always emits per-channel sum/sumsq partials; optionally stores Y;
//      optionally emits per-(b,m) max/min partials instead of storing. ----
template<bool BN_IN, bool STORE, bool MAXMIN>
__global__ __launch_bounds__(256)
void gemm_fused(const float* __restrict__ Wp, int Kp, int Kact, int M_,
                const float* __restrict__ bias,
                const float* __restrict__ X,
                const float* __restrict__ a_in, const float* __restrict__ sh_in,
                float* __restrict__ Y,
                float* __restrict__ psum, float* __restrict__ psq,
                float* __restrict__ pmax, float* __restrict__ pmin,
                int NC, int NITER)
{
    __shared__ __align__(16) float As[16][128];
    __shared__ __align__(16) float Bs[16][128];

    const int tid = threadIdx.x;
    const int tx = tid & 15, ty = tid >> 4;
    const int nc = blockIdx.x, mt = blockIdx.y, b = blockIdx.z;
    const int m0 = mt * 128;
    const int KT = Kp >> 4;

    float bv[8];
#pragma unroll
    for (int i = 0; i < 8; ++i) bv[i] = bias[m0 + ty * 8 + i];

    float sA[8], sQ[8], mx[8], mn[8];
#pragma unroll
    for (int i = 0; i < 8; ++i) { sA[i] = 0.f; sQ[i] = 0.f; mx[i] = -FLT_BIG; mn[i] = FLT_BIG; }

    const int arow = tid >> 1;            // 0..127
    const int akq  = (tid & 1) * 8;       // 0 or 8
    const int brow = tid >> 4;            // 0..15
    const int bc   = (tid & 15) * 8;      // 0..120

    float acc[8][8];

    for (int it = 0; it < NITER; ++it) {
        const int n0 = (nc * NITER + it) * 128;
#pragma unroll
        for (int i = 0; i < 8; ++i)
#pragma unroll
            for (int j = 0; j < 8; ++j) acc[i][j] = 0.f;

        for (int kt = 0; kt < KT; ++kt) {
            const int k0 = kt * 16;
            __syncthreads();
            // stage A: W[m0+arow][k0+akq .. +7]
            {
                const float4* wsrc = (const float4*)(Wp + (size_t)(m0 + arow) * Kp + k0 + akq);
                float4 a0 = wsrc[0];
                float4 a1 = wsrc[1];
                As[akq + 0][arow] = a0.x; As[akq + 1][arow] = a0.y;
                As[akq + 2][arow] = a0.z; As[akq + 3][arow] = a0.w;
                As[akq + 4][arow] = a1.x; As[akq + 5][arow] = a1.y;
                As[akq + 6][arow] = a1.z; As[akq + 7][arow] = a1.w;
            }
            // stage B: X[b][k0+brow][n0+bc .. +7], with optional BN+ReLU
            {
                const int k = k0 + brow;
                float4 b0 = {0.f, 0.f, 0.f, 0.f}, b1 = {0.f, 0.f, 0.f, 0.f};
                if (k < Kact) {
                    const float4* xsrc = (const float4*)(X + ((size_t)b * Kact + k) * NPTS + n0 + bc);
                    b0 = xsrc[0]; b1 = xsrc[1];
                    if (BN_IN) {
                        const float ak = a_in[k], sk = sh_in[k];
                        b0.x = fmaxf(fmaf(ak, b0.x, sk), 0.f);
                        b0.y = fmaxf(fmaf(ak, b0.y, sk), 0.f);
                        b0.z = fmaxf(fmaf(ak, b0.z, sk), 0.f);
                        b0.w = fmaxf(fmaf(ak, b0.w, sk), 0.f);
                        b1.x = fmaxf(fmaf(ak, b1.x, sk), 0.f);
                        b1.y = fmaxf(fmaf(ak, b1.y, sk), 0.f);
                        b1.z = fmaxf(fmaf(ak, b1.z, sk), 0.f);
                        b1.w = fmaxf(fmaf(ak, b1.w, sk), 0.f);
                    }
                }
                *(float4*)&Bs[brow][bc]     = b0;
                *(float4*)&Bs[brow][bc + 4] = b1;
            }
            __syncthreads();
#pragma unroll
            for (int kk = 0; kk < 16; ++kk) {
                const float4 A0 = *(const float4*)&As[kk][ty * 8];
                const float4 A1 = *(const float4*)&As[kk][ty * 8 + 4];
                const float4 B0 = *(const float4*)&Bs[kk][tx * 8];
                const float4 B1 = *(const float4*)&Bs[kk][tx * 8 + 4];
                const float av[8] = {A0.x, A0.y, A0.z, A0.w, A1.x, A1.y, A1.z, A1.w};
                const float bw[8] = {B0.x, B0.y, B0.z, B0.w, B1.x, B1.y, B1.z, B1.w};
#pragma unroll
                for (int i = 0; i < 8; ++i)
#pragma unroll
                    for (int j = 0; j < 8; ++j)
                        acc[i][j] = fmaf(av[i], bw[j], acc[i][j]);
            }
        }
        // epilogue for this n-tile
#pragma unroll
        for (int i = 0; i < 8; ++i) {
            float vr[8];
            float rs = 0.f, rq = 0.f;
#pragma unroll
            for (int j = 0; j < 8; ++j) {
                float v = acc[i][j] + bv[i];
                vr[j] = v;
                rs += v;
                rq = fmaf(v, v, rq);
                if (MAXMIN) { mx[i] = fmaxf(mx[i], v); mn[i] = fminf(mn[i], v); }
            }
            sA[i] += rs; sQ[i] += rq;
            if (STORE) {
                const size_t base = ((size_t)b * M_ + (m0 + ty * 8 + i)) * NPTS + n0 + tx * 8;
                float4 s0 = {vr[0], vr[1], vr[2], vr[3]};
                float4 s1 = {vr[4], vr[5], vr[6], vr[7]};
                *(float4*)(Y + base)     = s0;
                *(float4*)(Y + base + 4) = s1;
            }
        }
    }
    // butterfly-reduce across the 16 tx lanes (same ty -> same rows)
#pragma unroll
    for (int i = 0; i < 8; ++i) {
#pragma unroll
        for (int s = 1; s < 16; s <<= 1) {
            sA[i] += __shfl_xor(sA[i], s);
            sQ[i] += __shfl_xor(sQ[i], s);
            if (MAXMIN) {
                mx[i] = fmaxf(mx[i], __shfl_xor(mx[i], s));
                mn[i] = fminf(mn[i], __shfl_xor(mn[i], s));
            }
        }
    }
    if (tx == 0) {
        const int slot = b * NC + nc;
#pragma unroll
        for (int i = 0; i < 8; ++i) {
            const int m = m0 + ty * 8 + i;
            psum[(size_t)slot * M_ + m] = sA[i];
            psq[(size_t)slot * M_ + m]  = sQ[i];
            if (MAXMIN) {
                pmax[((size_t)b * M_ + m) * NC + nc] = mx[i];
                pmin[((size_t)b * M_ + m) * NC + nc] = mn[i];
            }
        }
    }
}

// ---- per-channel stats -> BN scale/shift:  a = g/sqrt(var+eps), sh = be - a*mean ----
__global__ void stats_k(const float* __restrict__ psum, const float* __restrict__ psq,
                        int M_, int slots,
                        const float* __restrict__ g, const float* __restrict__ be,
                        float* __restrict__ a_out, float* __restrict__ sh_out)
{
    int m = blockIdx.x * 256 + threadIdx.x;
    if (m >= M_) return;
    double s = 0.0, q = 0.0;
    for (int i = 0; i < slots; ++i) {
        s += (double)psum[(size_t)i * M_ + m];
        q += (double)psq[(size_t)i * M_ + m];
    }
    const double cnt = (double)NB * (double)NPTS;
    double mean = s / cnt;
    double var  = q / cnt - mean * mean;
    if (var < 0.0) var = 0.0;
    double a = (double)g[m] / sqrt(var + 1e-5);
    a_out[m]  = (float)a;
    sh_out[m] = (float)((double)be[m] - a * mean);
}

// ---- final: select max/min per (b,c), BN-apply+ReLU, then BN1d over batch ----
__global__ void final_k(const float* __restrict__ a3, const float* __restrict__ sh3,
                        const float* __restrict__ pmax, const float* __restrict__ pmin, int NC,
                        const float* __restrict__ g4, const float* __restrict__ be4,
                        float* __restrict__ out)
{
    int c = blockIdx.x * 256 + threadIdx.x;
    if (c >= 1024) return;
    const float a = a3[c], sh = sh3[c];
    float h[NB];
    float s = 0.f;
    for (int b = 0; b < NB; ++b) {
        float mxv = -FLT_BIG, mnv = FLT_BIG;
        for (int q = 0; q < NC; ++q) {
            mxv = fmaxf(mxv, pmax[((size_t)b * 1024 + c) * NC + q]);
            mnv = fminf(mnv, pmin[((size_t)b * 1024 + c) * NC + q]);
        }
        float v = (a >= 0.f) ? fmaf(a, mxv, sh) : fmaf(a, mnv, sh);
        h[b] = fmaxf(v, 0.f);
        s += h[b];
    }
    const float mean = s * (1.f / NB);
    float var = 0.f;
    for (int b = 0; b < NB; ++b) { float d = h[b] - mean; var = fmaf(d, d, var); }
    var *= (1.f / NB);
    const double ai = (double)g4[c] / sqrt((double)var + 1e-5);
    for (int b = 0; b < NB; ++b)
        out[b * 1024 + c] = (float)(ai * ((double)h[b] - (double)mean) + (double)be4[c]);
}

extern "C" void kernel_launch(void* const* d_in, const int* in_sizes, int n_in,
                              void* d_out, int out_size, void* d_ws, size_t ws_size,
                              hipStream_t stream) {
    const float* xyz = (const float*)d_in[0];
    const float* W1  = (const float*)d_in[1];
    const float* b1  = (const float*)d_in[2];
    const float* g1  = (const float*)d_in[3];
    const float* be1 = (const float*)d_in[4];
    const float* W2  = (const float*)d_in[5];
    const float* b2  = (const float*)d_in[6];
    const float* g2  = (const float*)d_in[7];
    const float* be2 = (const float*)d_in[8];
    const float* W3  = (const float*)d_in[9];
    const float* b3  = (const float*)d_in[10];
    const float* g3  = (const float*)d_in[11];
    const float* be3 = (const float*)d_in[12];
    const float* g4  = (const float*)d_in[13];
    const float* be4 = (const float*)d_in[14];

    float* ws  = (float*)d_ws;
    float* y1  = ws + OFF_Y1;
    float* y2  = ws + OFF_Y2;
    float* w1p = ws + OFF_W1P;
    float* a1v = ws + OFF_A1;  float* sh1 = ws + OFF_SH1;
    float* a2v = ws + OFF_A2;  float* sh2 = ws + OFF_SH2;
    float* a3v = ws + OFF_A3;  float* sh3 = ws + OFF_SH3;
    float* p1s = ws + OFF_P1S; float* p1q = ws + OFF_P1Q;
    float* p2s = ws + OFF_P2S; float* p2q = ws + OFF_P2Q;
    float* p3s = ws + OFF_P3S; float* p3q = ws + OFF_P3Q;
    float* pmx = ws + OFF_PMX; float* pmn = ws + OFF_PMN;

    float* out = (float*)d_out;

    // 0) pad W1 to K=656
    pad_w1_k<<<656, 256, 0, stream>>>(W1, w1p);

    // 1) L1: y1 = W1 @ xyz + b1  (store + stats).  grid: (NC=16, mt=2, b=16), NITER=2
    gemm_fused<false, true, false><<<dim3(16, 2, 16), 256, 0, stream>>>(
        w1p, 656, 643, 256, b1, xyz, nullptr, nullptr,
        y1, p1s, p1q, nullptr, nullptr, 16, 2);
    stats_k<<<1, 256, 0, stream>>>(p1s, p1q, 256, 16 * 16, g1, be1, a1v, sh1);

    // 2) L2: y2 = W2 @ relu(bn(y1)) + b2.  grid: (NC=8, mt=4, b=16), NITER=4
    gemm_fused<true, true, false><<<dim3(8, 4, 16), 256, 0, stream>>>(
        W2, 256, 256, 512, b2, y1, a1v, sh1,
        y2, p2s, p2q, nullptr, nullptr, 8, 4);
    stats_k<<<2, 256, 0, stream>>>(p2s, p2q, 512, 16 * 8, g2, be2, a2v, sh2);

    // 3) L3: stats + per-(b,m) max/min of y3 = W3 @ relu(bn(y2)) + b3 (no store).
    //    grid: (NC=4, mt=8, b=16), NITER=8
    gemm_fused<true, false, true><<<dim3(4, 8, 16), 256, 0, stream>>>(
        W3, 512, 512, 1024, b3, y2, a2v, sh2,
        nullptr, p3s, p3q, pmx, pmn, 4, 8);
    stats_k<<<4, 256, 0, stream>>>(p3s, p3q, 1024, 16 * 4, g3, be3, a3v, sh3);

    // 4) pool-select + final BN1d
    final_k<<<4, 256, 0, stream>>>(a3v, sh3, pmx, pmn, 4, g4, be4, out);
}

// Round 3
// 811.530 us; speedup vs baseline: 2.3687x; 2.3687x over previous
//
#include <hip/hip_runtime.h>
#include <math.h>

typedef unsigned short u16;
typedef unsigned int   u32;
typedef __attribute__((ext_vector_type(8))) short short8;
typedef __attribute__((ext_vector_type(4))) float f32x4;

#define NPTS 4096
#define NB   16
#define FLT_BIG 3.402823466e38f

// ---- workspace layout (float offsets) ----
static const size_t OFF_Y1  = 0;                          // 16*256*4096
static const size_t OFF_Y2  = 16777216;                   // 16*512*4096
static const size_t OFF_W1I = 50331648;                   // 516096 u16 = 258048 f32
static const size_t OFF_W2I = 50589696;                   // 393216 u16 = 196608 f32
static const size_t OFF_W3I = 50786304;                   // 1572864 u16 = 786432 f32
static const size_t OFF_PS  = 51572736;                   // 1,048,576
static const size_t OFF_PQ  = 52621312;                   // 1,048,576
static const size_t OFF_PMX = 53669888;                   // 1,048,576
static const size_t OFF_PMN = 54718464;                   // 1,048,576
static const size_t OFF_AC  = 55767040;                   // 1024
static const size_t OFF_SHC = 55768064;                   // 1024
// total = 55,769,088 f32 = ~223 MB

__device__ __forceinline__ u16 f2bf(float x) {
    u32 u = __float_as_uint(x);
    u32 r = (u + 0x7FFFu + ((u >> 16) & 1u)) >> 16;
    return (u16)r;
}
__device__ __forceinline__ float bf2f(u16 h) {
    return __uint_as_float(((u32)h) << 16);
}
__device__ __forceinline__ void gload_lds16(const void* g, void* l) {
    __builtin_amdgcn_global_load_lds(
        (const __attribute__((address_space(1))) u32*)g,
        (__attribute__((address_space(3))) u32*)l, 16, 0, 0);
}

// ---- split W into 3-plane LDS-image:  img[mt][kt][plane][128 m][32 k] bf16 ----
__global__ __launch_bounds__(256) void prep_w(const float* __restrict__ W, int Kact, int KT,
                                              u16* __restrict__ img) {
    const int bx = blockIdx.x;
    const int mt = bx / KT, kt = bx % KT;
    const int t = threadIdx.x;
    const int ml = t >> 1, kl0 = (t & 1) * 16;
    const int m = mt * 128 + ml;
    const size_t obase = ((size_t)(mt * KT + kt) * 3) * 4096 + (size_t)ml * 32 + kl0;
#pragma unroll
    for (int j = 0; j < 16; ++j) {
        const int k = kt * 32 + kl0 + j;
        const float w = (k < Kact) ? W[(size_t)m * Kact + k] : 0.f;
        const u16 h = f2bf(w);
        const float r1 = w - bf2f(h);
        const u16 md = f2bf(r1);
        const float r2 = r1 - bf2f(md);
        const u16 lo = f2bf(r2);
        img[obase + j]        = h;
        img[obase + 4096 + j] = md;
        img[obase + 8192 + j] = lo;
    }
}

// ---- fused split-bf16 MFMA GEMM (6 plane-products), BN+ReLU on input, stats/max epilogue ----
template<bool BN_IN, bool STORE, bool MAXMIN>
__global__ __launch_bounds__(256)
void gemm6(const u16* __restrict__ Wimg, int KT, int Kact, int M_,
           const float* __restrict__ bias,
           const float* __restrict__ X,            // [NB][Kact][4096] fp32
           const float* __restrict__ a_in, const float* __restrict__ sh_in,
           float* __restrict__ Y,
           float* __restrict__ psum, float* __restrict__ psq,
           float* __restrict__ pmax, float* __restrict__ pmin, int NT)
{
    __shared__ __align__(16) u16 AsU[3 * 128 * 32];   // plane-major [3][128 m][32 k]
    __shared__ __align__(16) u16 BsU[3 * 128 * 32];   // plane-major [3][128 n][32 k]

    const int tid  = threadIdx.x;
    const int lane = tid & 63, wid = tid >> 6;
    const int l15 = lane & 15, l4 = lane >> 4;
    const int wm = wid >> 1, wn = wid & 1;
    const int nt = blockIdx.x, mtb = blockIdx.y, b = blockIdx.z;
    const int m0 = mtb * 128, n0 = nt * 128;

    // B-staging mapping
    const int kl = tid & 31;               // k within tile
    const int ngrp = tid >> 5;             // 0..7 -> 16 consecutive n

    f32x4 acc[4][4];
#pragma unroll
    for (int i = 0; i < 4; ++i)
#pragma unroll
        for (int j = 0; j < 4; ++j) acc[i][j] = (f32x4){0.f, 0.f, 0.f, 0.f};

    for (int kt = 0; kt < KT; ++kt) {
        // ---- stage A (3 planes, 24KB) via global_load_lds ----
        {
            const u16* gb = Wimg + (size_t)(mtb * KT + kt) * 12288;
#pragma unroll
            for (int i = 0; i < 6; ++i) {
                const u16* gsrc = gb + i * 2048 + wid * 512 + lane * 8;
                u16* ldst = AsU + i * 2048 + wid * 512;     // wave-uniform; HW adds lane*16B
                gload_lds16(gsrc, ldst);
            }
        }
        // ---- stage B: read fp32 X, BN+ReLU, 3-way split, transposed scatter [n][k] ----
        {
            const int kglob = kt * 32 + kl;
            float xv[16];
            if (kglob < Kact) {
                const float4* xs = (const float4*)(X + ((size_t)b * Kact + kglob) * NPTS + n0 + ngrp * 16);
#pragma unroll
                for (int c = 0; c < 4; ++c) {
                    float4 f = xs[c];
                    xv[4 * c + 0] = f.x; xv[4 * c + 1] = f.y; xv[4 * c + 2] = f.z; xv[4 * c + 3] = f.w;
                }
                if (BN_IN) {
                    const float ak = a_in[kglob], sk = sh_in[kglob];
#pragma unroll
                    for (int e = 0; e < 16; ++e) xv[e] = fmaxf(fmaf(ak, xv[e], sk), 0.f);
                }
            } else {
#pragma unroll
                for (int e = 0; e < 16; ++e) xv[e] = 0.f;
            }
#pragma unroll
            for (int e = 0; e < 16; ++e) {
                const float v = xv[e];
                const u16 h = f2bf(v);
                const float r1 = v - bf2f(h);
                const u16 md = f2bf(r1);
                const float r2 = r1 - bf2f(md);
                const u16 lo = f2bf(r2);
                const int nl = ngrp * 16 + e;
                BsU[nl * 32 + kl]        = h;
                BsU[4096 + nl * 32 + kl] = md;
                BsU[8192 + nl * 32 + kl] = lo;
            }
        }
        __syncthreads();

        // ---- compute: cache A-frags (3 planes x 4 mf), stream B-frags ----
        short8 af[3][4];
#pragma unroll
        for (int p = 0; p < 3; ++p)
#pragma unroll
            for (int mf = 0; mf < 4; ++mf)
                af[p][mf] = *(const short8*)(AsU + p * 4096 + (wm * 64 + mf * 16 + l15) * 32 + l4 * 8);

#pragma unroll
        for (int pb = 0; pb < 3; ++pb) {
            const int npa = (pb == 0) ? 3 : ((pb == 1) ? 2 : 1);
#pragma unroll
            for (int nf = 0; nf < 4; ++nf) {
                const short8 bfv = *(const short8*)(BsU + pb * 4096 + (wn * 64 + nf * 16 + l15) * 32 + l4 * 8);
#pragma unroll
                for (int pa = 0; pa < 3; ++pa) {
                    if (pa < npa) {
#pragma unroll
                        for (int mf = 0; mf < 4; ++mf)
                            acc[mf][nf] = __builtin_amdgcn_mfma_f32_16x16x32_bf16(
                                af[pa][mf], bfv, acc[mf][nf], 0, 0, 0);
                    }
                }
            }
        }
        __syncthreads();
    }

    // ---- epilogue: bias, stats partials, optional store / max-min partials ----
#pragma unroll
    for (int mf = 0; mf < 4; ++mf) {
#pragma unroll
        for (int r = 0; r < 4; ++r) {
            const int m = m0 + wm * 64 + mf * 16 + l4 * 4 + r;
            const float bvv = bias[m];
            float vs[4];
            float rs = 0.f, rq = 0.f;
#pragma unroll
            for (int nf = 0; nf < 4; ++nf) {
                const float v = acc[mf][nf][r] + bvv;
                vs[nf] = v; rs += v; rq = fmaf(v, v, rq);
            }
            float mx = 0.f, mn = 0.f;
            if (MAXMIN) {
                mx = fmaxf(fmaxf(vs[0], vs[1]), fmaxf(vs[2], vs[3]));
                mn = fminf(fminf(vs[0], vs[1]), fminf(vs[2], vs[3]));
            }
            if (STORE) {
#pragma unroll
                for (int nf = 0; nf < 4; ++nf)
                    Y[((size_t)b * M_ + m) * NPTS + n0 + wn * 64 + nf * 16 + l15] = vs[nf];
            }
#pragma unroll
            for (int s = 1; s < 16; s <<= 1) {
                rs += __shfl_xor(rs, s);
                rq += __shfl_xor(rq, s);
                if (MAXMIN) {
                    mx = fmaxf(mx, __shfl_xor(mx, s));
                    mn = fminf(mn, __shfl_xor(mn, s));
                }
            }
            if (l15 == 0) {
                const int slot = (b * NT + nt) * 2 + wn;
                psum[(size_t)slot * M_ + m] = rs;
                psq[(size_t)slot * M_ + m]  = rq;
                if (MAXMIN) {
                    pmax[((size_t)b * M_ + m) * 64 + nt * 2 + wn] = mx;
                    pmin[((size_t)b * M_ + m) * 64 + nt * 2 + wn] = mn;
                }
            }
        }
    }
}

// ---- per-channel stats (1024 slots) -> BN scale/shift ----
__global__ __launch_bounds__(256) void stats_k(const float* __restrict__ psum, const float* __restrict__ psq,
                                               int M_,
                                               const float* __restrict__ g, const float* __restrict__ be,
                                               float* __restrict__ a_out, float* __restrict__ sh_out)
{
    __shared__ double ds[4][64];
    __shared__ double dq[4][64];
    const int mloc = threadIdx.x & 63, q = threadIdx.x >> 6;
    const int m = blockIdx.x * 64 + mloc;
    double s = 0.0, sq = 0.0;
    for (int sl = q * 256; sl < (q + 1) * 256; ++sl) {
        s  += (double)psum[(size_t)sl * M_ + m];
        sq += (double)psq[(size_t)sl * M_ + m];
    }
    ds[q][mloc] = s; dq[q][mloc] = sq;
    __syncthreads();
    if (threadIdx.x < 64) {
        const double S = ds[0][mloc] + ds[1][mloc] + ds[2][mloc] + ds[3][mloc];
        const double Q = dq[0][mloc] + dq[1][mloc] + dq[2][mloc] + dq[3][mloc];
        const double cnt = (double)NB * (double)NPTS;
        double mean = S / cnt;
        double var  = Q / cnt - mean * mean;
        if (var < 0.0) var = 0.0;
        const double a = (double)g[m] / sqrt(var + 1e-5);
        a_out[m]  = (float)a;
        sh_out[m] = (float)((double)be[m] - a * mean);
    }
}

// ---- final: select max/min per (b,c), BN-apply+ReLU, then BN1d over batch ----
__global__ __launch_bounds__(256) void final_k(const float* __restrict__ ac, const float* __restrict__ shc,
                                               const float* __restrict__ pmax, const float* __restrict__ pmin,
                                               const float* __restrict__ g4, const float* __restrict__ be4,
                                               float* __restrict__ out)
{
    const int c = blockIdx.x * 256 + threadIdx.x;
    if (c >= 1024) return;
    const float a = ac[c], sh = shc[c];
    float h[NB];
    float s = 0.f;
    for (int b = 0; b < NB; ++b) {
        float mxv = -FLT_BIG, mnv = FLT_BIG;
        const float* pxr = pmax + ((size_t)b * 1024 + c) * 64;
        const float* pnr = pmin + ((size_t)b * 1024 + c) * 64;
        for (int q = 0; q < 64; ++q) {
            mxv = fmaxf(mxv, pxr[q]);
            mnv = fminf(mnv, pnr[q]);
        }
        const float v = (a >= 0.f) ? fmaf(a, mxv, sh) : fmaf(a, mnv, sh);
        h[b] = fmaxf(v, 0.f);
        s += h[b];
    }
    const float mean = s * (1.f / NB);
    float var = 0.f;
    for (int b = 0; b < NB; ++b) { const float d = h[b] - mean; var = fmaf(d, d, var); }
    var *= (1.f / NB);
    const double ai = (double)g4[c] / sqrt((double)var + 1e-5);
    for (int b = 0; b < NB; ++b)
        out[b * 1024 + c] = (float)(ai * ((double)h[b] - (double)mean) + (double)be4[c]);
}

extern "C" void kernel_launch(void* const* d_in, const int* in_sizes, int n_in,
                              void* d_out, int out_size, void* d_ws, size_t ws_size,
                              hipStream_t stream) {
    const float* xyz = (const float*)d_in[0];
    const float* W1  = (const float*)d_in[1];
    const float* b1  = (const float*)d_in[2];
    const float* g1  = (const float*)d_in[3];
    const float* be1 = (const float*)d_in[4];
    const float* W2  = (const float*)d_in[5];
    const float* b2  = (const float*)d_in[6];
    const float* g2  = (const float*)d_in[7];
    const float* be2 = (const float*)d_in[8];
    const float* W3  = (const float*)d_in[9];
    const float* b3  = (const float*)d_in[10];
    const float* g3  = (const float*)d_in[11];
    const float* be3 = (const float*)d_in[12];
    const float* g4  = (const float*)d_in[13];
    const float* be4 = (const float*)d_in[14];

    float* ws = (float*)d_ws;
    float* y1  = ws + OFF_Y1;
    float* y2  = ws + OFF_Y2;
    u16*   w1i = (u16*)(ws + OFF_W1I);
    u16*   w2i = (u16*)(ws + OFF_W2I);
    u16*   w3i = (u16*)(ws + OFF_W3I);
    float* ps  = ws + OFF_PS;
    float* pq  = ws + OFF_PQ;
    float* pmx = ws + OFF_PMX;
    float* pmn = ws + OFF_PMN;
    float* ac  = ws + OFF_AC;
    float* shc = ws + OFF_SHC;
    float* out = (float*)d_out;

    // W-plane images:  L1 KT=21 (K 643->672), L2 KT=8, L3 KT=16
    prep_w<<<2 * 21, 256, 0, stream>>>(W1, 643, 21, w1i);
    prep_w<<<4 * 8,  256, 0, stream>>>(W2, 256, 8,  w2i);
    prep_w<<<8 * 16, 256, 0, stream>>>(W3, 512, 16, w3i);

    // L1: y1 = W1 @ xyz + b1 (store + stats)
    gemm6<false, true, false><<<dim3(32, 2, 16), 256, 0, stream>>>(
        w1i, 21, 643, 256, b1, xyz, nullptr, nullptr,
        y1, ps, pq, nullptr, nullptr, 32);
    stats_k<<<4, 256, 0, stream>>>(ps, pq, 256, g1, be1, ac, shc);

    // L2: y2 = W2 @ relu(bn(y1)) + b2 (store + stats)
    gemm6<true, true, false><<<dim3(32, 4, 16), 256, 0, stream>>>(
        w2i, 8, 256, 512, b2, y1, ac, shc,
        y2, ps, pq, nullptr, nullptr, 32);
    stats_k<<<8, 256, 0, stream>>>(ps, pq, 512, g2, be2, ac, shc);

    // L3: stats + per-(b,m) max/min partials (no store)
    gemm6<true, false, true><<<dim3(32, 8, 16), 256, 0, stream>>>(
        w3i, 16, 512, 1024, b3, y2, ac, shc,
        nullptr, ps, pq, pmx, pmn, 32);
    stats_k<<<16, 256, 0, stream>>>(ps, pq, 1024, g3, be3, ac, shc);

    // pool-select + final BN1d
    final_k<<<4, 256, 0, stream>>>(ac, shc, pmx, pmn, g4, be4, out);
}